// Round 1
// baseline (32321.753 us; speedup 1.0000x reference)
//
#include <hip/hip_runtime.h>
#include <hip/hip_bf16.h>
#include <cmath>

// BiLSTM-CRF inference. S=8192 tokens, E=512 embed, H=512 per dir (4H=2048 gates),
// T=32 tags. Pipeline: [fused gather+input-proj GEMM] -> [2x32-WG spin-synced LSTM
// recurrence, W_hh in registers] -> [FC] -> [sequential exact Viterbi].

#define S_LEN 8192
#define E_DIM 512
#define H_DIM 512
#define G4    2048
#define TAGS  32
#define NWG   32          // workgroups per LSTM direction
#define START_TAG 30
#define STOP_TAG  31
#define NEGV  (-10000.0f)

typedef float fx4 __attribute__((ext_vector_type(4)));
typedef unsigned long long u64;

// ---------------------------------------------------------------------------
// Kernel 1: xp[dir][m][n] = dot(embed[tok(m)], W_ih[n]) + b[n]
// tok(m) = inputs[m] for fwd, inputs[S-1-m] for bwd. 64x64 tile, K-chunks of 32.
// ---------------------------------------------------------------------------
__global__ __launch_bounds__(256) void xp_gemm(
    const int* __restrict__ inputs, const float* __restrict__ embed,
    const float* __restrict__ Wf, const float* __restrict__ bf,
    const float* __restrict__ Wb, const float* __restrict__ bb,
    float* __restrict__ xp)
{
  const int dir = blockIdx.z;
  const float* Wt = dir ? Wb : Wf;
  const float* bs = dir ? bb : bf;
  float* out = xp + (size_t)dir * S_LEN * G4;
  const int n0 = blockIdx.x * 64, m0 = blockIdx.y * 64;

  __shared__ float As[32][68];   // [k][m], pad 68 keeps rows 16B-aligned
  __shared__ float Bs[32][68];   // [k][n]
  __shared__ int toks[64];

  const int tid = threadIdx.x;
  if (tid < 64) {
    int m = m0 + tid;
    toks[tid] = inputs[dir ? (S_LEN - 1 - m) : m];
  }
  __syncthreads();

  const int r  = tid >> 2;           // 0..63 : row loaded by this thread
  const int kq = (tid & 3) * 8;      // k offset within chunk
  const int tm = tid >> 4;           // 0..15 : micro-tile m
  const int tn = tid & 15;           // 0..15 : micro-tile n

  float acc[4][4] = {};
  for (int k0 = 0; k0 < E_DIM; k0 += 32) {
    const float* ap = embed + (size_t)toks[r] * E_DIM + k0 + kq;
    fx4 a0 = *(const fx4*)ap;
    fx4 a1 = *(const fx4*)(ap + 4);
    const float* bpt = Wt + (size_t)(n0 + r) * E_DIM + k0 + kq;
    fx4 b0 = *(const fx4*)bpt;
    fx4 b1 = *(const fx4*)(bpt + 4);
    __syncthreads();   // previous iteration's LDS reads done
    As[kq+0][r]=a0.x; As[kq+1][r]=a0.y; As[kq+2][r]=a0.z; As[kq+3][r]=a0.w;
    As[kq+4][r]=a1.x; As[kq+5][r]=a1.y; As[kq+6][r]=a1.z; As[kq+7][r]=a1.w;
    Bs[kq+0][r]=b0.x; Bs[kq+1][r]=b0.y; Bs[kq+2][r]=b0.z; Bs[kq+3][r]=b0.w;
    Bs[kq+4][r]=b1.x; Bs[kq+5][r]=b1.y; Bs[kq+6][r]=b1.z; Bs[kq+7][r]=b1.w;
    __syncthreads();
    #pragma unroll
    for (int k = 0; k < 32; ++k) {
      fx4 av = *(const fx4*)&As[k][tm*4];
      fx4 bv = *(const fx4*)&Bs[k][tn*4];
      acc[0][0]=fmaf(av.x,bv.x,acc[0][0]); acc[0][1]=fmaf(av.x,bv.y,acc[0][1]);
      acc[0][2]=fmaf(av.x,bv.z,acc[0][2]); acc[0][3]=fmaf(av.x,bv.w,acc[0][3]);
      acc[1][0]=fmaf(av.y,bv.x,acc[1][0]); acc[1][1]=fmaf(av.y,bv.y,acc[1][1]);
      acc[1][2]=fmaf(av.y,bv.z,acc[1][2]); acc[1][3]=fmaf(av.y,bv.w,acc[1][3]);
      acc[2][0]=fmaf(av.z,bv.x,acc[2][0]); acc[2][1]=fmaf(av.z,bv.y,acc[2][1]);
      acc[2][2]=fmaf(av.z,bv.z,acc[2][2]); acc[2][3]=fmaf(av.z,bv.w,acc[2][3]);
      acc[3][0]=fmaf(av.w,bv.x,acc[3][0]); acc[3][1]=fmaf(av.w,bv.y,acc[3][1]);
      acc[3][2]=fmaf(av.w,bv.z,acc[3][2]); acc[3][3]=fmaf(av.w,bv.w,acc[3][3]);
    }
  }
  const int gn = n0 + tn*4;
  fx4 bias = *(const fx4*)&bs[gn];
  #pragma unroll
  for (int i = 0; i < 4; ++i) {
    fx4 res;
    res.x = acc[i][0] + bias.x; res.y = acc[i][1] + bias.y;
    res.z = acc[i][2] + bias.z; res.w = acc[i][3] + bias.w;
    *(fx4*)&out[(size_t)(m0 + tm*4 + i) * G4 + gn] = res;
  }
}

// ---------------------------------------------------------------------------
// Kernel 2: sequential LSTM, both directions concurrently.
// 64 blocks x 256 thr. Block (dir, j): owns h outputs [j*16, j*16+16) ->
// 64 rows of W_hh (i,f,g,o slices) held in REGISTERS (128 f32/thread).
// Per step: spin on producer flags (AGENT scope, LLC), bypass-load h_{t-1},
// matvec, activations, c/h update, publish h + release flag.
// ---------------------------------------------------------------------------
__global__ __launch_bounds__(256, 1) void lstm_seq(
    const float* __restrict__ Whh_f, const float* __restrict__ Whh_b,
    const float* __restrict__ xp, float* __restrict__ h_hist,
    int* __restrict__ flags)
{
  const int bid = blockIdx.x;
  const int dir = bid >> 5, j = bid & 31;
  const float* Whh = dir ? Whh_b : Whh_f;
  const float* xpd = xp + (size_t)dir * S_LEN * G4;
  float* hh = h_hist + (size_t)dir * S_LEN * H_DIM;
  int* flg = flags + dir * NWG;

  const int tid  = threadIdx.x;
  const int q    = tid & 3;        // which 128-wide K quarter
  const int lrow = tid >> 2;       // 0..63 local gate row
  const int gate = lrow >> 4;      // 0=i 1=f 2=g 3=o
  const int mm   = lrow & 15;      // h index within this WG's slice
  const int grow = gate * 512 + j * 16 + mm;   // global gate row
  const int lane = tid & 63;
  const int wid  = tid >> 6;

  // W_hh slice into registers: 32 x fx4 = 128 floats
  fx4 wreg[32];
  {
    const fx4* wp = (const fx4*)(Whh + (size_t)grow * H_DIM + q * 128);
    #pragma unroll
    for (int k = 0; k < 32; ++k) wreg[k] = wp[k];
  }

  __shared__ __align__(16) float hprev[512];
  __shared__ float gates_lds[64];
  __shared__ float c_lds[16];
  if (tid < 16) c_lds[tid] = 0.f;
  __syncthreads();

  for (int t = 0; t < S_LEN; ++t) {
    // prefetch this step's xp value (normal load; issued before the spin)
    float xpv = xpd[(size_t)t * G4 + grow];

    if (t > 0 && wid == 0) {
      // lane L loads h[L*8..L*8+8) which lives in chunk L/2 -> wait that flag
      int* fp = flg + (lane >> 1);
      while (__hip_atomic_load(fp, __ATOMIC_RELAXED, __HIP_MEMORY_SCOPE_AGENT) < t) { }
      u64* hp = (u64*)(hh + (size_t)(t - 1) * H_DIM + lane * 8);
      u64 d0 = __hip_atomic_load(hp + 0, __ATOMIC_RELAXED, __HIP_MEMORY_SCOPE_AGENT);
      u64 d1 = __hip_atomic_load(hp + 1, __ATOMIC_RELAXED, __HIP_MEMORY_SCOPE_AGENT);
      u64 d2 = __hip_atomic_load(hp + 2, __ATOMIC_RELAXED, __HIP_MEMORY_SCOPE_AGENT);
      u64 d3 = __hip_atomic_load(hp + 3, __ATOMIC_RELAXED, __HIP_MEMORY_SCOPE_AGENT);
      union { u64 u; float f[2]; } c0, c1, c2, c3;
      c0.u = d0; c1.u = d1; c2.u = d2; c3.u = d3;
      float* hdst = &hprev[lane * 8];
      hdst[0]=c0.f[0]; hdst[1]=c0.f[1]; hdst[2]=c1.f[0]; hdst[3]=c1.f[1];
      hdst[4]=c2.f[0]; hdst[5]=c2.f[1]; hdst[6]=c3.f[0]; hdst[7]=c3.f[1];
    }
    __syncthreads();

    float a0=0.f, a1=0.f, a2=0.f, a3=0.f;
    if (t > 0) {
      const fx4* hv4 = (const fx4*)&hprev[q * 128];
      #pragma unroll
      for (int k = 0; k < 32; ++k) {
        fx4 hv = hv4[k];
        a0 = fmaf(wreg[k].x, hv.x, a0);
        a1 = fmaf(wreg[k].y, hv.y, a1);
        a2 = fmaf(wreg[k].z, hv.z, a2);
        a3 = fmaf(wreg[k].w, hv.w, a3);
      }
    }
    float acc = (a0 + a1) + (a2 + a3);
    acc += __shfl_xor(acc, 1);
    acc += __shfl_xor(acc, 2);
    if (q == 0) {
      float g = acc + xpv;
      gates_lds[lrow] = (gate == 2) ? tanhf(g) : 1.f / (1.f + expf(-g));
    }
    __syncthreads();
    if (tid < 16) {
      float iv = gates_lds[tid],      fv = gates_lds[16 + tid];
      float gv = gates_lds[32 + tid], ov = gates_lds[48 + tid];
      float cval = fv * c_lds[tid] + iv * gv;
      c_lds[tid] = cval;
      float hval = ov * tanhf(cval);
      __hip_atomic_store(hh + (size_t)t * H_DIM + j * 16 + tid, hval,
                         __ATOMIC_RELAXED, __HIP_MEMORY_SCOPE_AGENT);
    }
    if (tid == 0) {
      // release: drains the wave's h stores before the flag becomes visible
      __hip_atomic_store(flg + j, t + 1, __ATOMIC_RELEASE, __HIP_MEMORY_SCOPE_AGENT);
    }
    __syncthreads();
  }
}

// ---------------------------------------------------------------------------
// Kernel 3: feats[s][j] = dot(concat(h_f[s], h_b_pos[s]), fcW[j]) + fcb[j]
// h_b_pos[s] = h_b_step[S-1-s]. One block per s.
// ---------------------------------------------------------------------------
__global__ __launch_bounds__(256) void fc_feats(
    const float* __restrict__ h_hist, const float* __restrict__ fcW,
    const float* __restrict__ fcb, float* __restrict__ feats)
{
  const int s = blockIdx.x;
  const int tid = threadIdx.x;
  __shared__ __align__(16) float hcat[1024];
  __shared__ float red[8][32];
  const float* hf = h_hist + (size_t)s * H_DIM;
  const float* hb = h_hist + (size_t)S_LEN * H_DIM + (size_t)(S_LEN - 1 - s) * H_DIM;
  hcat[tid]       = hf[tid];
  hcat[256 + tid] = hf[256 + tid];
  hcat[512 + tid] = hb[tid];
  hcat[768 + tid] = hb[256 + tid];
  __syncthreads();
  const int jj = tid & 31, part = tid >> 5;
  const float* wr = fcW + (size_t)jj * 1024 + part * 128;
  float a = 0.f;
  #pragma unroll
  for (int k = 0; k < 128; k += 4) {
    fx4 wv = *(const fx4*)(wr + k);
    a = fmaf(wv.x, hcat[part*128 + k + 0], a);
    a = fmaf(wv.y, hcat[part*128 + k + 1], a);
    a = fmaf(wv.z, hcat[part*128 + k + 2], a);
    a = fmaf(wv.w, hcat[part*128 + k + 3], a);
  }
  red[part][jj] = a;
  __syncthreads();
  if (tid < 32) {
    float sum = fcb[tid];
    #pragma unroll
    for (int p = 0; p < 8; ++p) sum += red[p][tid];
    feats[(size_t)s * TAGS + tid] = sum;
  }
}

// ---------------------------------------------------------------------------
// Kernel 4: exact sequential Viterbi (matches jnp.argmax first-index ties).
// 1 block x 64 thr: lane = ph*32+j handles next-tag j, prev-half ph.
// Backtrack staged through LDS in 1024-step chunks.
// ---------------------------------------------------------------------------
__global__ __launch_bounds__(64) void viterbi(
    const float* __restrict__ feats, const float* __restrict__ trans,
    unsigned char* __restrict__ bpg, float* __restrict__ out)
{
  const int lane = threadIdx.x;
  const int j = lane & 31, ph = lane >> 5;
  float tc[16];
  #pragma unroll
  for (int p = 0; p < 16; ++p) tc[p] = trans[(ph*16 + p) * TAGS + j];

  __shared__ float prev[32];
  if (lane < 32) prev[lane] = (lane == START_TAG) ? 0.f : NEGV;
  __syncthreads();

  for (int t = 0; t < S_LEN; ++t) {
    float feat = feats[(size_t)t * TAGS + j];
    float best = -3.4e38f; int bpi = 0;
    #pragma unroll
    for (int p = 0; p < 16; ++p) {                 // ascending p, strict > ==> first max
      float sc = prev[ph*16 + p] + tc[p];
      if (sc > best) { best = sc; bpi = ph*16 + p; }
    }
    float ob  = __shfl_xor(best, 32);
    int   obp = __shfl_xor(bpi, 32);
    if (ob > best || (ob == best && obp < bpi)) { best = ob; bpi = obp; }
    __syncthreads();
    if (lane < 32) {
      bpg[(size_t)t * TAGS + j] = (unsigned char)bpi;
      prev[j] = best + feat;                        // emit added AFTER argmax (ref quirk)
    }
    __syncthreads();
  }

  // termination + argmax (first-index)
  float term = (lane < 32) ? prev[lane] + trans[lane * TAGS + STOP_TAG] : -3.4e38f;
  int idx = lane;
  #pragma unroll
  for (int off = 32; off >= 1; off >>= 1) {
    float os = __shfl_down(term, off);
    int   oi = __shfl_down(idx, off);
    if (os > term || (os == term && oi < idx)) { term = os; idx = oi; }
  }
  __shared__ int s_cur;
  if (lane == 0) {
    out[0] = term;                      // path_score
    out[1 + (S_LEN - 1)] = (float)idx;  // last tag
    s_cur = idx;
  }

  // backtrack: stage bp rows through LDS, walk on lane 0
  __shared__ __align__(16) unsigned char bpc[1024 * TAGS];   // 32 KB
  for (int ch = 7; ch >= 0; --ch) {
    __syncthreads();
    const int4* src = (const int4*)(bpg + (size_t)ch * 1024 * TAGS);
    int4* dst = (int4*)bpc;
    for (int i = lane; i < 2048; i += 64) dst[i] = src[i];
    __syncthreads();
    if (lane == 0) {
      int cur = s_cur;
      const int tlo = ch * 1024;
      for (int tt = 1023; tt >= 0; --tt) {
        int t = tlo + tt;
        if (t == 0) break;              // bp[0] unused
        cur = bpc[tt * TAGS + cur];     // path[t-1] = bp[t][path[t]]
        out[1 + (t - 1)] = (float)cur;
      }
      s_cur = cur;
    }
  }
}

// ---------------------------------------------------------------------------
extern "C" void kernel_launch(void* const* d_in, const int* in_sizes, int n_in,
                              void* d_out, int out_size, void* d_ws, size_t ws_size,
                              hipStream_t stream)
{
  (void)in_sizes; (void)n_in; (void)out_size; (void)ws_size;
  const int*   inputs = (const int*)d_in[0];
  const float* embed  = (const float*)d_in[1];
  const float* Wih_f  = (const float*)d_in[2];
  const float* Whh_f  = (const float*)d_in[3];
  const float* b_f    = (const float*)d_in[4];
  const float* Wih_b  = (const float*)d_in[5];
  const float* Whh_b  = (const float*)d_in[6];
  const float* b_b    = (const float*)d_in[7];
  const float* fcW    = (const float*)d_in[8];
  const float* fcb    = (const float*)d_in[9];
  const float* trans  = (const float*)d_in[10];
  float* out = (float*)d_out;

  // workspace layout (floats)
  float* ws     = (float*)d_ws;
  float* xp     = ws;                                   // [2][S][2048]  128 MB
  float* h_hist = xp + (size_t)2 * S_LEN * G4;          // [2][S][512]    32 MB
  float* feats  = h_hist + (size_t)2 * S_LEN * H_DIM;   // [S][32]         1 MB
  int*   flags  = (int*)(feats + (size_t)S_LEN * TAGS); // [64]
  unsigned char* bp = (unsigned char*)(flags + 64);     // [S][32]       256 KB

  hipMemsetAsync(flags, 0, 64 * sizeof(int), stream);

  dim3 ggrid(G4 / 64, S_LEN / 64, 2);
  xp_gemm<<<ggrid, 256, 0, stream>>>(inputs, embed, Wih_f, b_f, Wih_b, b_b, xp);
  lstm_seq<<<64, 256, 0, stream>>>(Whh_f, Whh_b, xp, h_hist, flags);
  fc_feats<<<S_LEN, 256, 0, stream>>>(h_hist, fcW, fcb, feats);
  viterbi<<<1, 64, 0, stream>>>(feats, trans, bp, out);
}

// Round 2
// 17150.754 us; speedup vs baseline: 1.8846x; 1.8846x over previous
//
#include <hip/hip_runtime.h>
#include <hip/hip_bf16.h>
#include <cmath>

// BiLSTM-CRF inference. S=8192 tokens, E=512 embed, H=512 per dir (4H=2048 gates),
// T=32 tags. Pipeline: [fused gather+input-proj GEMM] -> [2x32-WG spin-synced LSTM
// recurrence with version-embedded u64 (val,cnt) ring exchange] -> [FC] -> [Viterbi].

#define S_LEN 8192
#define E_DIM 512
#define H_DIM 512
#define G4    2048
#define TAGS  32
#define NWG   32          // workgroups per LSTM direction
#define START_TAG 30
#define STOP_TAG  31
#define NEGV  (-10000.0f)

typedef float fx4 __attribute__((ext_vector_type(4)));
typedef unsigned long long u64;

// ---------------------------------------------------------------------------
// Kernel 1: xp[dir][m][n] = dot(embed[tok(m)], W_ih[n]) + b[n]
// tok(m) = inputs[m] for fwd, inputs[S-1-m] for bwd. 64x64 tile, K-chunks of 32.
// ---------------------------------------------------------------------------
__global__ __launch_bounds__(256) void xp_gemm(
    const int* __restrict__ inputs, const float* __restrict__ embed,
    const float* __restrict__ Wf, const float* __restrict__ bf,
    const float* __restrict__ Wb, const float* __restrict__ bb,
    float* __restrict__ xp)
{
  const int dir = blockIdx.z;
  const float* Wt = dir ? Wb : Wf;
  const float* bs = dir ? bb : bf;
  float* out = xp + (size_t)dir * S_LEN * G4;
  const int n0 = blockIdx.x * 64, m0 = blockIdx.y * 64;

  __shared__ float As[32][68];   // [k][m], pad 68 keeps rows 16B-aligned
  __shared__ float Bs[32][68];   // [k][n]
  __shared__ int toks[64];

  const int tid = threadIdx.x;
  if (tid < 64) {
    int m = m0 + tid;
    toks[tid] = inputs[dir ? (S_LEN - 1 - m) : m];
  }
  __syncthreads();

  const int r  = tid >> 2;           // 0..63 : row loaded by this thread
  const int kq = (tid & 3) * 8;      // k offset within chunk
  const int tm = tid >> 4;           // 0..15 : micro-tile m
  const int tn = tid & 15;           // 0..15 : micro-tile n

  float acc[4][4] = {};
  for (int k0 = 0; k0 < E_DIM; k0 += 32) {
    const float* ap = embed + (size_t)toks[r] * E_DIM + k0 + kq;
    fx4 a0 = *(const fx4*)ap;
    fx4 a1 = *(const fx4*)(ap + 4);
    const float* bpt = Wt + (size_t)(n0 + r) * E_DIM + k0 + kq;
    fx4 b0 = *(const fx4*)bpt;
    fx4 b1 = *(const fx4*)(bpt + 4);
    __syncthreads();   // previous iteration's LDS reads done
    As[kq+0][r]=a0.x; As[kq+1][r]=a0.y; As[kq+2][r]=a0.z; As[kq+3][r]=a0.w;
    As[kq+4][r]=a1.x; As[kq+5][r]=a1.y; As[kq+6][r]=a1.z; As[kq+7][r]=a1.w;
    Bs[kq+0][r]=b0.x; Bs[kq+1][r]=b0.y; Bs[kq+2][r]=b0.z; Bs[kq+3][r]=b0.w;
    Bs[kq+4][r]=b1.x; Bs[kq+5][r]=b1.y; Bs[kq+6][r]=b1.z; Bs[kq+7][r]=b1.w;
    __syncthreads();
    #pragma unroll
    for (int k = 0; k < 32; ++k) {
      fx4 av = *(const fx4*)&As[k][tm*4];
      fx4 bv = *(const fx4*)&Bs[k][tn*4];
      acc[0][0]=fmaf(av.x,bv.x,acc[0][0]); acc[0][1]=fmaf(av.x,bv.y,acc[0][1]);
      acc[0][2]=fmaf(av.x,bv.z,acc[0][2]); acc[0][3]=fmaf(av.x,bv.w,acc[0][3]);
      acc[1][0]=fmaf(av.y,bv.x,acc[1][0]); acc[1][1]=fmaf(av.y,bv.y,acc[1][1]);
      acc[1][2]=fmaf(av.y,bv.z,acc[1][2]); acc[1][3]=fmaf(av.y,bv.w,acc[1][3]);
      acc[2][0]=fmaf(av.z,bv.x,acc[2][0]); acc[2][1]=fmaf(av.z,bv.y,acc[2][1]);
      acc[2][2]=fmaf(av.z,bv.z,acc[2][2]); acc[2][3]=fmaf(av.z,bv.w,acc[2][3]);
      acc[3][0]=fmaf(av.w,bv.x,acc[3][0]); acc[3][1]=fmaf(av.w,bv.y,acc[3][1]);
      acc[3][2]=fmaf(av.w,bv.z,acc[3][2]); acc[3][3]=fmaf(av.w,bv.w,acc[3][3]);
    }
  }
  const int gn = n0 + tn*4;
  fx4 bias = *(const fx4*)&bs[gn];
  #pragma unroll
  for (int i = 0; i < 4; ++i) {
    fx4 res;
    res.x = acc[i][0] + bias.x; res.y = acc[i][1] + bias.y;
    res.z = acc[i][2] + bias.z; res.w = acc[i][3] + bias.w;
    *(fx4*)&out[(size_t)(m0 + tm*4 + i) * G4 + gn] = res;
  }
}

// ---------------------------------------------------------------------------
// Kernel 2: sequential LSTM, both directions concurrently. 64 blocks x 256 thr.
// Block (dir,j) owns h[j*16..j*16+16) -> 64 gate rows. Wave w owns K-quarter
// [w*128,(w+1)*128): it polls the u64 (cnt<<32|f32) ring for its quarter of
// h_{t-1}, stages to its private LDS segment (wave-internal lgkmcnt, no
// barrier), broadcast-read matvec (conflict-free), partial to LDS. ONE
// __syncthreads; wave 0 reduces, activates, updates c (registers), publishes
// h as relaxed u64 stores (version embedded => no release/vmcnt drain).
// Ring depth 2 (slot=t&1): overwrite provably happens only after all blocks
// consumed the overwritten step.
// ---------------------------------------------------------------------------
__global__ __launch_bounds__(256, 1) void lstm_seq(
    const float* __restrict__ Whh_f, const float* __restrict__ Whh_b,
    const float* __restrict__ xp, float* __restrict__ h_hist,
    u64* __restrict__ ring)
{
  const int bid = blockIdx.x;
  const int dir = bid >> 5, j = bid & 31;
  const float* Whh = dir ? Whh_b : Whh_f;
  const float* xpd = xp + (size_t)dir * S_LEN * G4;
  float* hh = h_hist + (size_t)dir * S_LEN * H_DIM;
  u64* rg = ring + (size_t)dir * 2 * H_DIM;   // [2 slots][512]

  const int tid  = threadIdx.x;
  const int lane = tid & 63;
  const int wid  = tid >> 6;                  // wave = K-quarter owner
  // lane L <-> gate row L of this block: gate = L>>4, mm = L&15
  const int gate = lane >> 4;
  const int mm   = lane & 15;
  const int grow = gate * 512 + j * 16 + mm;  // global gate row

  // W_hh slice: row `grow`, K in [wid*128, wid*128+128) -> 32 fx4 / lane
  fx4 wreg[32];
  {
    const fx4* wp = (const fx4*)(Whh + (size_t)grow * H_DIM + wid * 128);
    #pragma unroll
    for (int k = 0; k < 32; ++k) wreg[k] = wp[k];
  }

  __shared__ __align__(16) float hq[4][128];     // per-wave staged h quarter
  __shared__ float partial[2][4][64];            // [t&1][wave][row]
  u64* my_ring0 = rg + (size_t)wid * 128 + lane * 2;  // slot stride added per step

  float c_reg = 0.f;                             // cell state, lanes<16 of wave 0

  for (int t = 0; t < S_LEN; ++t) {
    const int tb = t & 1;
    float xpv = 0.f;
    if (wid == 0) xpv = xpd[(size_t)t * G4 + grow];   // prefetch (HBM) before poll

    fx4 accv = {0.f, 0.f, 0.f, 0.f};
    if (t > 0) {
      // ---- poll own quarter of h_{t-1} (slot (t-1)&1, cnt == t) ----
      u64* rp = rg + (size_t)((t - 1) & 1) * H_DIM + wid * 128 + lane * 2;
      const unsigned want = (unsigned)t;
      u64 p0 = __hip_atomic_load(rp + 0, __ATOMIC_RELAXED, __HIP_MEMORY_SCOPE_AGENT);
      u64 p1 = __hip_atomic_load(rp + 1, __ATOMIC_RELAXED, __HIP_MEMORY_SCOPE_AGENT);
      while ((unsigned)(p0 >> 32) < want || (unsigned)(p1 >> 32) < want) {
        p0 = __hip_atomic_load(rp + 0, __ATOMIC_RELAXED, __HIP_MEMORY_SCOPE_AGENT);
        p1 = __hip_atomic_load(rp + 1, __ATOMIC_RELAXED, __HIP_MEMORY_SCOPE_AGENT);
      }
      union { unsigned u; float f; } v0, v1;
      v0.u = (unsigned)p0; v1.u = (unsigned)p1;
      hq[wid][lane * 2]     = v0.f;
      hq[wid][lane * 2 + 1] = v1.f;
      asm volatile("s_waitcnt lgkmcnt(0)" ::: "memory");  // wave-internal visibility
      __builtin_amdgcn_sched_barrier(0);

      // ---- matvec over own quarter: broadcast LDS reads, conflict-free ----
      const fx4* hv4 = (const fx4*)&hq[wid][0];
      #pragma unroll
      for (int k = 0; k < 32; ++k) {
        fx4 hv = hv4[k];
        accv.x = fmaf(wreg[k].x, hv.x, accv.x);
        accv.y = fmaf(wreg[k].y, hv.y, accv.y);
        accv.z = fmaf(wreg[k].z, hv.z, accv.z);
        accv.w = fmaf(wreg[k].w, hv.w, accv.w);
      }
    }
    partial[tb][wid][lane] = (accv.x + accv.y) + (accv.z + accv.w);
    __syncthreads();                             // the ONE barrier per step

    if (wid == 0) {
      float g = partial[tb][0][lane] + partial[tb][1][lane]
              + partial[tb][2][lane] + partial[tb][3][lane] + xpv;
      float act = (gate == 2) ? tanhf(g) : 1.f / (1.f + expf(-g));
      // gather i,f,g,o for h-index mm via cross-lane shuffles
      float fv = __shfl(act, mm + 16);
      float gv = __shfl(act, mm + 32);
      float ov = __shfl(act, mm + 48);
      if (lane < 16) {
        float cval = fv * c_reg + act * gv;      // act == i for lanes<16
        c_reg = cval;
        float hval = ov * tanhf(cval);
        hh[(size_t)t * H_DIM + j * 16 + lane] = hval;   // for fc_feats (plain)
        union { float f; unsigned u; } hb; hb.f = hval;
        u64 pkt = ((u64)(unsigned)(t + 1) << 32) | hb.u;
        __hip_atomic_store(rg + (size_t)tb * H_DIM + j * 16 + lane, pkt,
                           __ATOMIC_RELAXED, __HIP_MEMORY_SCOPE_AGENT);
      }
    }
    // no second barrier: partial is double-buffered by tb; hq is wave-private.
  }
  (void)my_ring0;
}

// ---------------------------------------------------------------------------
// Kernel 3: feats[s][j] = dot(concat(h_f[s], h_b_pos[s]), fcW[j]) + fcb[j]
// h_b_pos[s] = h_b_step[S-1-s]. One block per s.
// ---------------------------------------------------------------------------
__global__ __launch_bounds__(256) void fc_feats(
    const float* __restrict__ h_hist, const float* __restrict__ fcW,
    const float* __restrict__ fcb, float* __restrict__ feats)
{
  const int s = blockIdx.x;
  const int tid = threadIdx.x;
  __shared__ __align__(16) float hcat[1024];
  __shared__ float red[8][32];
  const float* hf = h_hist + (size_t)s * H_DIM;
  const float* hb = h_hist + (size_t)S_LEN * H_DIM + (size_t)(S_LEN - 1 - s) * H_DIM;
  hcat[tid]       = hf[tid];
  hcat[256 + tid] = hf[256 + tid];
  hcat[512 + tid] = hb[tid];
  hcat[768 + tid] = hb[256 + tid];
  __syncthreads();
  const int jj = tid & 31, part = tid >> 5;
  const float* wr = fcW + (size_t)jj * 1024 + part * 128;
  float a = 0.f;
  #pragma unroll
  for (int k = 0; k < 128; k += 4) {
    fx4 wv = *(const fx4*)(wr + k);
    a = fmaf(wv.x, hcat[part*128 + k + 0], a);
    a = fmaf(wv.y, hcat[part*128 + k + 1], a);
    a = fmaf(wv.z, hcat[part*128 + k + 2], a);
    a = fmaf(wv.w, hcat[part*128 + k + 3], a);
  }
  red[part][jj] = a;
  __syncthreads();
  if (tid < 32) {
    float sum = fcb[tid];
    #pragma unroll
    for (int p = 0; p < 8; ++p) sum += red[p][tid];
    feats[(size_t)s * TAGS + tid] = sum;
  }
}

// ---------------------------------------------------------------------------
// Kernel 4: exact sequential Viterbi (matches jnp.argmax first-index ties).
// 1 block x 64 thr: lane = ph*32+j handles next-tag j, prev-half ph.
// feat row software-prefetched one step ahead; backtrack staged through LDS.
// ---------------------------------------------------------------------------
__global__ __launch_bounds__(64) void viterbi(
    const float* __restrict__ feats, const float* __restrict__ trans,
    unsigned char* __restrict__ bpg, float* __restrict__ out)
{
  const int lane = threadIdx.x;
  const int j = lane & 31, ph = lane >> 5;
  float tc[16];
  #pragma unroll
  for (int p = 0; p < 16; ++p) tc[p] = trans[(ph*16 + p) * TAGS + j];

  __shared__ float prev[32];
  if (lane < 32) prev[lane] = (lane == START_TAG) ? 0.f : NEGV;
  __syncthreads();

  float feat = feats[j];                        // t = 0
  for (int t = 0; t < S_LEN; ++t) {
    float featn = (t + 1 < S_LEN) ? feats[(size_t)(t + 1) * TAGS + j] : 0.f;
    float best = -3.4e38f; int bpi = 0;
    #pragma unroll
    for (int p = 0; p < 16; ++p) {                 // ascending p, strict > ==> first max
      float sc = prev[ph*16 + p] + tc[p];
      if (sc > best) { best = sc; bpi = ph*16 + p; }
    }
    float ob  = __shfl_xor(best, 32);
    int   obp = __shfl_xor(bpi, 32);
    if (ob > best || (ob == best && obp < bpi)) { best = ob; bpi = obp; }
    __syncthreads();
    if (lane < 32) {
      bpg[(size_t)t * TAGS + j] = (unsigned char)bpi;
      prev[j] = best + feat;                        // emit added AFTER argmax (ref quirk)
    }
    __syncthreads();
    feat = featn;
  }

  // termination + argmax (first-index)
  float term = (lane < 32) ? prev[lane] + trans[lane * TAGS + STOP_TAG] : -3.4e38f;
  int idx = lane;
  #pragma unroll
  for (int off = 32; off >= 1; off >>= 1) {
    float os = __shfl_down(term, off);
    int   oi = __shfl_down(idx, off);
    if (os > term || (os == term && oi < idx)) { term = os; idx = oi; }
  }
  __shared__ int s_cur;
  if (lane == 0) {
    out[0] = term;                      // path_score
    out[1 + (S_LEN - 1)] = (float)idx;  // last tag
    s_cur = idx;
  }

  // backtrack: stage bp rows through LDS, walk on lane 0
  __shared__ __align__(16) unsigned char bpc[1024 * TAGS];   // 32 KB
  for (int ch = 7; ch >= 0; --ch) {
    __syncthreads();
    const int4* src = (const int4*)(bpg + (size_t)ch * 1024 * TAGS);
    int4* dst = (int4*)bpc;
    for (int i = lane; i < 2048; i += 64) dst[i] = src[i];
    __syncthreads();
    if (lane == 0) {
      int cur = s_cur;
      const int tlo = ch * 1024;
      for (int tt = 1023; tt >= 0; --tt) {
        int t = tlo + tt;
        if (t == 0) break;              // bp[0] unused
        cur = bpc[tt * TAGS + cur];     // path[t-1] = bp[t][path[t]]
        out[1 + (t - 1)] = (float)cur;
      }
      s_cur = cur;
    }
  }
}

// ---------------------------------------------------------------------------
extern "C" void kernel_launch(void* const* d_in, const int* in_sizes, int n_in,
                              void* d_out, int out_size, void* d_ws, size_t ws_size,
                              hipStream_t stream)
{
  (void)in_sizes; (void)n_in; (void)out_size; (void)ws_size;
  const int*   inputs = (const int*)d_in[0];
  const float* embed  = (const float*)d_in[1];
  const float* Wih_f  = (const float*)d_in[2];
  const float* Whh_f  = (const float*)d_in[3];
  const float* b_f    = (const float*)d_in[4];
  const float* Wih_b  = (const float*)d_in[5];
  const float* Whh_b  = (const float*)d_in[6];
  const float* b_b    = (const float*)d_in[7];
  const float* fcW    = (const float*)d_in[8];
  const float* fcb    = (const float*)d_in[9];
  const float* trans  = (const float*)d_in[10];
  float* out = (float*)d_out;

  // workspace layout
  float* ws     = (float*)d_ws;
  float* xp     = ws;                                   // [2][S][2048]  128 MB
  float* h_hist = xp + (size_t)2 * S_LEN * G4;          // [2][S][512]    32 MB
  float* feats  = h_hist + (size_t)2 * S_LEN * H_DIM;   // [S][32]         1 MB
  unsigned char* bp = (unsigned char*)(feats + (size_t)S_LEN * TAGS); // [S][32] 256 KB
  u64*   ring   = (u64*)(bp + (size_t)S_LEN * TAGS);    // [2][2][512]    16 KB

  hipMemsetAsync(ring, 0, 2 * 2 * H_DIM * sizeof(u64), stream);

  dim3 ggrid(G4 / 64, S_LEN / 64, 2);
  xp_gemm<<<ggrid, 256, 0, stream>>>(inputs, embed, Wih_f, b_f, Wih_b, b_b, xp);
  lstm_seq<<<64, 256, 0, stream>>>(Whh_f, Whh_b, xp, h_hist, ring);
  fc_feats<<<S_LEN, 256, 0, stream>>>(h_hist, fcW, fcb, feats);
  viterbi<<<1, 64, 0, stream>>>(feats, trans, bp, out);
}

// Round 3
// 16819.862 us; speedup vs baseline: 1.9216x; 1.0197x over previous
//
#include <hip/hip_runtime.h>
#include <hip/hip_bf16.h>
#include <cmath>

// BiLSTM-CRF inference. S=8192 tokens, E=512 embed, H=512 per dir (4H=2048 gates),
// T=32 tags. Pipeline: [fused gather+input-proj GEMM] -> [2x32-WG spin-synced LSTM
// recurrence with version-embedded u64 (val,cnt) ring exchange] -> [FC] -> [Viterbi].

#define S_LEN 8192
#define E_DIM 512
#define H_DIM 512
#define G4    2048
#define TAGS  32
#define NWG   32          // workgroups per LSTM direction
#define START_TAG 30
#define STOP_TAG  31
#define NEGV  (-10000.0f)

typedef float fx4 __attribute__((ext_vector_type(4)));
typedef unsigned long long u64;

// fast activations: v_exp_f32 computes 2^x; sigmoid/tanh via exp2 + rcp.
// Guarded so a wrong builtin name can't kill the build.
#if __has_builtin(__builtin_amdgcn_exp2f)
__device__ __forceinline__ float fexp2(float x) { return __builtin_amdgcn_exp2f(x); }
#else
__device__ __forceinline__ float fexp2(float x) { return exp2f(x); }
#endif
#if __has_builtin(__builtin_amdgcn_rcpf)
__device__ __forceinline__ float frcp(float x) { return __builtin_amdgcn_rcpf(x); }
#else
__device__ __forceinline__ float frcp(float x) { return 1.f / x; }
#endif
#define LOG2E 1.44269504088896340736f
__device__ __forceinline__ float fsigmoid(float x) {
  return frcp(1.f + fexp2(-LOG2E * x));
}
__device__ __forceinline__ float ftanh(float x) {
  // tanh(x) = 2/(1+e^{-2x}) - 1
  return fmaf(2.f, frcp(1.f + fexp2(-2.f * LOG2E * x)), -1.f);
}

// ---------------------------------------------------------------------------
// Kernel 1: xp[dir][m][n] = dot(embed[tok(m)], W_ih[n]) + b[n]
// tok(m) = inputs[m] for fwd, inputs[S-1-m] for bwd. 64x64 tile, K-chunks of 32.
// ---------------------------------------------------------------------------
__global__ __launch_bounds__(256) void xp_gemm(
    const int* __restrict__ inputs, const float* __restrict__ embed,
    const float* __restrict__ Wf, const float* __restrict__ bf,
    const float* __restrict__ Wb, const float* __restrict__ bb,
    float* __restrict__ xp)
{
  const int dir = blockIdx.z;
  const float* Wt = dir ? Wb : Wf;
  const float* bs = dir ? bb : bf;
  float* out = xp + (size_t)dir * S_LEN * G4;
  const int n0 = blockIdx.x * 64, m0 = blockIdx.y * 64;

  __shared__ float As[32][68];   // [k][m], pad 68 keeps rows 16B-aligned
  __shared__ float Bs[32][68];   // [k][n]
  __shared__ int toks[64];

  const int tid = threadIdx.x;
  if (tid < 64) {
    int m = m0 + tid;
    toks[tid] = inputs[dir ? (S_LEN - 1 - m) : m];
  }
  __syncthreads();

  const int r  = tid >> 2;           // 0..63 : row loaded by this thread
  const int kq = (tid & 3) * 8;      // k offset within chunk
  const int tm = tid >> 4;           // 0..15 : micro-tile m
  const int tn = tid & 15;           // 0..15 : micro-tile n

  float acc[4][4] = {};
  for (int k0 = 0; k0 < E_DIM; k0 += 32) {
    const float* ap = embed + (size_t)toks[r] * E_DIM + k0 + kq;
    fx4 a0 = *(const fx4*)ap;
    fx4 a1 = *(const fx4*)(ap + 4);
    const float* bpt = Wt + (size_t)(n0 + r) * E_DIM + k0 + kq;
    fx4 b0 = *(const fx4*)bpt;
    fx4 b1 = *(const fx4*)(bpt + 4);
    __syncthreads();   // previous iteration's LDS reads done
    As[kq+0][r]=a0.x; As[kq+1][r]=a0.y; As[kq+2][r]=a0.z; As[kq+3][r]=a0.w;
    As[kq+4][r]=a1.x; As[kq+5][r]=a1.y; As[kq+6][r]=a1.z; As[kq+7][r]=a1.w;
    Bs[kq+0][r]=b0.x; Bs[kq+1][r]=b0.y; Bs[kq+2][r]=b0.z; Bs[kq+3][r]=b0.w;
    Bs[kq+4][r]=b1.x; Bs[kq+5][r]=b1.y; Bs[kq+6][r]=b1.z; Bs[kq+7][r]=b1.w;
    __syncthreads();
    #pragma unroll
    for (int k = 0; k < 32; ++k) {
      fx4 av = *(const fx4*)&As[k][tm*4];
      fx4 bv = *(const fx4*)&Bs[k][tn*4];
      acc[0][0]=fmaf(av.x,bv.x,acc[0][0]); acc[0][1]=fmaf(av.x,bv.y,acc[0][1]);
      acc[0][2]=fmaf(av.x,bv.z,acc[0][2]); acc[0][3]=fmaf(av.x,bv.w,acc[0][3]);
      acc[1][0]=fmaf(av.y,bv.x,acc[1][0]); acc[1][1]=fmaf(av.y,bv.y,acc[1][1]);
      acc[1][2]=fmaf(av.y,bv.z,acc[1][2]); acc[1][3]=fmaf(av.y,bv.w,acc[1][3]);
      acc[2][0]=fmaf(av.z,bv.x,acc[2][0]); acc[2][1]=fmaf(av.z,bv.y,acc[2][1]);
      acc[2][2]=fmaf(av.z,bv.z,acc[2][2]); acc[2][3]=fmaf(av.z,bv.w,acc[2][3]);
      acc[3][0]=fmaf(av.w,bv.x,acc[3][0]); acc[3][1]=fmaf(av.w,bv.y,acc[3][1]);
      acc[3][2]=fmaf(av.w,bv.z,acc[3][2]); acc[3][3]=fmaf(av.w,bv.w,acc[3][3]);
    }
  }
  const int gn = n0 + tn*4;
  fx4 bias = *(const fx4*)&bs[gn];
  #pragma unroll
  for (int i = 0; i < 4; ++i) {
    fx4 res;
    res.x = acc[i][0] + bias.x; res.y = acc[i][1] + bias.y;
    res.z = acc[i][2] + bias.z; res.w = acc[i][3] + bias.w;
    *(fx4*)&out[(size_t)(m0 + tm*4 + i) * G4 + gn] = res;
  }
}

// ---------------------------------------------------------------------------
// Kernel 2: sequential LSTM, both directions concurrently. 64 blocks x 256 thr.
// Block (dir,j) owns h[j*16..j*16+16) -> 64 gate rows. Wave w owns K-quarter
// [w*128,(w+1)*128): 2-deep pipelined poll of the u64 (cnt<<32|f32) ring,
// stage to wave-private LDS, broadcast-read matvec (conflict-free), partial to
// LDS. ONE __syncthreads; wave 0 reduces (own partial in regs), fast-math
// activations, c in registers, publishes h as relaxed u64 (version embedded).
// ---------------------------------------------------------------------------
__global__ __launch_bounds__(256, 1) void lstm_seq(
    const float* __restrict__ Whh_f, const float* __restrict__ Whh_b,
    const float* __restrict__ xp, float* __restrict__ h_hist,
    u64* __restrict__ ring)
{
  const int bid = blockIdx.x;
  const int dir = bid >> 5, j = bid & 31;
  const float* Whh = dir ? Whh_b : Whh_f;
  const float* xpd = xp + (size_t)dir * S_LEN * G4;
  float* hh = h_hist + (size_t)dir * S_LEN * H_DIM;
  u64* rg = ring + (size_t)dir * 2 * H_DIM;   // [2 slots][512]

  const int tid  = threadIdx.x;
  const int lane = tid & 63;
  const int wid  = tid >> 6;                  // wave = K-quarter owner
  const int gate = lane >> 4;                 // 0=i 1=f 2=g 3=o
  const int mm   = lane & 15;                 // h index within this WG's slice
  const int grow = gate * 512 + j * 16 + mm;  // global gate row

  // W_hh slice: row `grow`, K in [wid*128, wid*128+128) -> 32 fx4 / lane
  fx4 wreg[32];
  {
    const fx4* wp = (const fx4*)(Whh + (size_t)grow * H_DIM + wid * 128);
    #pragma unroll
    for (int k = 0; k < 32; ++k) wreg[k] = wp[k];
  }
  // Pin W in VGPRs: opaque asm outputs cannot be re-materialized from memory
  // inside the t-loop (the "memory"-clobber waitcnt would otherwise license
  // the compiler to sink/reload these 128 values every step).
  #pragma unroll
  for (int k = 0; k < 32; ++k) asm volatile("" : "+v"(wreg[k]));

  __shared__ __align__(16) float hq[4][128];     // per-wave staged h quarter
  __shared__ float partial[2][4][64];            // [t&1][wave][row]

  float c_reg = 0.f;                             // cell state, lanes<16 of wave 0
  float xpv = 0.f;
  if (wid == 0) xpv = xpd[grow];                 // t = 0 input projection

  for (int t = 0; t < S_LEN; ++t) {
    const int tb = t & 1;
    // prefetch next step's xp a full step early (LLC/HBM latency off the chain)
    float xpn = 0.f;
    if (wid == 0 && t + 1 < S_LEN) xpn = xpd[(size_t)(t + 1) * G4 + grow];

    fx4 accv = {0.f, 0.f, 0.f, 0.f};
    if (t > 0) {
      // ---- 2-deep pipelined poll of own quarter (slot (t-1)&1, cnt == t) ----
      u64* rp = rg + (size_t)((t - 1) & 1) * H_DIM + wid * 128 + lane * 2;
      const unsigned want = (unsigned)t;
      u64 p0 = __hip_atomic_load(rp + 0, __ATOMIC_RELAXED, __HIP_MEMORY_SCOPE_AGENT);
      u64 p1 = __hip_atomic_load(rp + 1, __ATOMIC_RELAXED, __HIP_MEMORY_SCOPE_AGENT);
      u64 q0 = __hip_atomic_load(rp + 0, __ATOMIC_RELAXED, __HIP_MEMORY_SCOPE_AGENT);
      u64 q1 = __hip_atomic_load(rp + 1, __ATOMIC_RELAXED, __HIP_MEMORY_SCOPE_AGENT);
      while ((unsigned)(p0 >> 32) < want || (unsigned)(p1 >> 32) < want) {
        p0 = q0; p1 = q1;      // check older pair; newer pair stays in flight
        q0 = __hip_atomic_load(rp + 0, __ATOMIC_RELAXED, __HIP_MEMORY_SCOPE_AGENT);
        q1 = __hip_atomic_load(rp + 1, __ATOMIC_RELAXED, __HIP_MEMORY_SCOPE_AGENT);
      }
      union { unsigned u; float f; } v0, v1;
      v0.u = (unsigned)p0; v1.u = (unsigned)p1;
      float2 hv2; hv2.x = v0.f; hv2.y = v1.f;
      ((float2*)&hq[wid][0])[lane] = hv2;
      asm volatile("s_waitcnt lgkmcnt(0)" ::: "memory");  // wave-internal visibility
      __builtin_amdgcn_sched_barrier(0);

      // ---- matvec over own quarter: broadcast LDS reads, conflict-free ----
      const fx4* hv4 = (const fx4*)&hq[wid][0];
      #pragma unroll
      for (int k = 0; k < 32; ++k) {
        fx4 hv = hv4[k];
        accv.x = fmaf(wreg[k].x, hv.x, accv.x);
        accv.y = fmaf(wreg[k].y, hv.y, accv.y);
        accv.z = fmaf(wreg[k].z, hv.z, accv.z);
        accv.w = fmaf(wreg[k].w, hv.w, accv.w);
      }
    }
    float mypart = (accv.x + accv.y) + (accv.z + accv.w);
    partial[tb][wid][lane] = mypart;
    __syncthreads();                             // the ONE barrier per step

    if (wid == 0) {
      float g = mypart + partial[tb][1][lane]
              + partial[tb][2][lane] + partial[tb][3][lane] + xpv;
      float act = (gate == 2) ? ftanh(g) : fsigmoid(g);
      // gather i,f,g,o for h-index mm via cross-lane shuffles
      float fv = __shfl(act, mm + 16);
      float gv = __shfl(act, mm + 32);
      float ov = __shfl(act, mm + 48);
      if (lane < 16) {
        float cval = fv * c_reg + act * gv;      // act == i for lanes<16
        c_reg = cval;
        float hval = ov * ftanh(cval);
        union { float f; unsigned u; } hb; hb.f = hval;
        u64 pkt = ((u64)(unsigned)(t + 1) << 32) | hb.u;
        __hip_atomic_store(rg + (size_t)tb * H_DIM + j * 16 + lane, pkt,
                           __ATOMIC_RELAXED, __HIP_MEMORY_SCOPE_AGENT);
        hh[(size_t)t * H_DIM + j * 16 + lane] = hval;   // for fc_feats (plain)
      }
    }
    xpv = xpn;   // forces the prefetch's vmcnt wait here, off the publish path
    // no second barrier: partial is double-buffered by tb; hq is wave-private.
  }
}

// ---------------------------------------------------------------------------
// Kernel 3: feats[s][j] = dot(concat(h_f[s], h_b_pos[s]), fcW[j]) + fcb[j]
// h_b_pos[s] = h_b_step[S-1-s]. One block per s.
// ---------------------------------------------------------------------------
__global__ __launch_bounds__(256) void fc_feats(
    const float* __restrict__ h_hist, const float* __restrict__ fcW,
    const float* __restrict__ fcb, float* __restrict__ feats)
{
  const int s = blockIdx.x;
  const int tid = threadIdx.x;
  __shared__ __align__(16) float hcat[1024];
  __shared__ float red[8][32];
  const float* hf = h_hist + (size_t)s * H_DIM;
  const float* hb = h_hist + (size_t)S_LEN * H_DIM + (size_t)(S_LEN - 1 - s) * H_DIM;
  hcat[tid]       = hf[tid];
  hcat[256 + tid] = hf[256 + tid];
  hcat[512 + tid] = hb[tid];
  hcat[768 + tid] = hb[256 + tid];
  __syncthreads();
  const int jj = tid & 31, part = tid >> 5;
  const float* wr = fcW + (size_t)jj * 1024 + part * 128;
  float a = 0.f;
  #pragma unroll
  for (int k = 0; k < 128; k += 4) {
    fx4 wv = *(const fx4*)(wr + k);
    a = fmaf(wv.x, hcat[part*128 + k + 0], a);
    a = fmaf(wv.y, hcat[part*128 + k + 1], a);
    a = fmaf(wv.z, hcat[part*128 + k + 2], a);
    a = fmaf(wv.w, hcat[part*128 + k + 3], a);
  }
  red[part][jj] = a;
  __syncthreads();
  if (tid < 32) {
    float sum = fcb[tid];
    #pragma unroll
    for (int p = 0; p < 8; ++p) sum += red[p][tid];
    feats[(size_t)s * TAGS + tid] = sum;
  }
}

// ---------------------------------------------------------------------------
// Kernel 4: exact sequential Viterbi (matches jnp.argmax first-index ties).
// 1 block x 64 thr: lane = ph*32+j handles next-tag j, prev-half ph.
// prev[] double-buffered -> ONE barrier per step; feat prefetched one step.
// ---------------------------------------------------------------------------
__global__ __launch_bounds__(64) void viterbi(
    const float* __restrict__ feats, const float* __restrict__ trans,
    unsigned char* __restrict__ bpg, float* __restrict__ out)
{
  const int lane = threadIdx.x;
  const int j = lane & 31, ph = lane >> 5;
  float tc[16];
  #pragma unroll
  for (int p = 0; p < 16; ++p) tc[p] = trans[(ph*16 + p) * TAGS + j];

  __shared__ float prev[2][32];
  if (lane < 32) prev[0][lane] = (lane == START_TAG) ? 0.f : NEGV;
  __syncthreads();

  float feat = feats[j];                        // t = 0
  for (int t = 0; t < S_LEN; ++t) {
    const int pb = t & 1;
    float featn = (t + 1 < S_LEN) ? feats[(size_t)(t + 1) * TAGS + j] : 0.f;
    float best = -3.4e38f; int bpi = 0;
    #pragma unroll
    for (int p = 0; p < 16; ++p) {                 // ascending p, strict > ==> first max
      float sc = prev[pb][ph*16 + p] + tc[p];
      if (sc > best) { best = sc; bpi = ph*16 + p; }
    }
    float ob  = __shfl_xor(best, 32);
    int   obp = __shfl_xor(bpi, 32);
    if (ob > best || (ob == best && obp < bpi)) { best = ob; bpi = obp; }
    if (lane < 32) {
      bpg[(size_t)t * TAGS + j] = (unsigned char)bpi;
      prev[pb ^ 1][j] = best + feat;                // emit added AFTER argmax (ref quirk)
    }
    __syncthreads();
    feat = featn;
  }

  // termination + argmax (first-index)
  float term = (lane < 32) ? prev[S_LEN & 1][lane] + trans[lane * TAGS + STOP_TAG]
                           : -3.4e38f;
  int idx = lane;
  #pragma unroll
  for (int off = 32; off >= 1; off >>= 1) {
    float os = __shfl_down(term, off);
    int   oi = __shfl_down(idx, off);
    if (os > term || (os == term && oi < idx)) { term = os; idx = oi; }
  }
  __shared__ int s_cur;
  if (lane == 0) {
    out[0] = term;                      // path_score
    out[1 + (S_LEN - 1)] = (float)idx;  // last tag
    s_cur = idx;
  }

  // backtrack: stage bp rows through LDS, walk on lane 0
  __shared__ __align__(16) unsigned char bpc[1024 * TAGS];   // 32 KB
  for (int ch = 7; ch >= 0; --ch) {
    __syncthreads();
    const int4* src = (const int4*)(bpg + (size_t)ch * 1024 * TAGS);
    int4* dst = (int4*)bpc;
    for (int i = lane; i < 2048; i += 64) dst[i] = src[i];
    __syncthreads();
    if (lane == 0) {
      int cur = s_cur;
      const int tlo = ch * 1024;
      for (int tt = 1023; tt >= 0; --tt) {
        int t = tlo + tt;
        if (t == 0) break;              // bp[0] unused
        cur = bpc[tt * TAGS + cur];     // path[t-1] = bp[t][path[t]]
        out[1 + (t - 1)] = (float)cur;
      }
      s_cur = cur;
    }
  }
}

// ---------------------------------------------------------------------------
extern "C" void kernel_launch(void* const* d_in, const int* in_sizes, int n_in,
                              void* d_out, int out_size, void* d_ws, size_t ws_size,
                              hipStream_t stream)
{
  (void)in_sizes; (void)n_in; (void)out_size; (void)ws_size;
  const int*   inputs = (const int*)d_in[0];
  const float* embed  = (const float*)d_in[1];
  const float* Wih_f  = (const float*)d_in[2];
  const float* Whh_f  = (const float*)d_in[3];
  const float* b_f    = (const float*)d_in[4];
  const float* Wih_b  = (const float*)d_in[5];
  const float* Whh_b  = (const float*)d_in[6];
  const float* b_b    = (const float*)d_in[7];
  const float* fcW    = (const float*)d_in[8];
  const float* fcb    = (const float*)d_in[9];
  const float* trans  = (const float*)d_in[10];
  float* out = (float*)d_out;

  // workspace layout
  float* ws     = (float*)d_ws;
  float* xp     = ws;                                   // [2][S][2048]  128 MB
  float* h_hist = xp + (size_t)2 * S_LEN * G4;          // [2][S][512]    32 MB
  float* feats  = h_hist + (size_t)2 * S_LEN * H_DIM;   // [S][32]         1 MB
  unsigned char* bp = (unsigned char*)(feats + (size_t)S_LEN * TAGS); // [S][32] 256 KB
  u64*   ring   = (u64*)(bp + (size_t)S_LEN * TAGS);    // [2][2][512]    16 KB

  hipMemsetAsync(ring, 0, 2 * 2 * H_DIM * sizeof(u64), stream);

  dim3 ggrid(G4 / 64, S_LEN / 64, 2);
  xp_gemm<<<ggrid, 256, 0, stream>>>(inputs, embed, Wih_f, b_f, Wih_b, b_b, xp);
  lstm_seq<<<64, 256, 0, stream>>>(Whh_f, Whh_b, xp, h_hist, ring);
  fc_feats<<<S_LEN, 256, 0, stream>>>(h_hist, fcW, fcb, feats);
  viterbi<<<1, 64, 0, stream>>>(feats, trans, bp, out);
}